// Round 1
// baseline (821.389 us; speedup 1.0000x reference)
//
#include <hip/hip_runtime.h>
#include <hip/hip_bf16.h>

#define NB 4
#define TT 2048
#define DD 1024
#define MM (NB*TT)
#define QBLK 32

using f32x4  = __attribute__((ext_vector_type(4))) float;
using bf16x8 = __attribute__((ext_vector_type(8))) __bf16;

__device__ __forceinline__ unsigned short f2b(float f) {
  __hip_bfloat16 h = __float2bfloat16(f);
  return *reinterpret_cast<unsigned short*>(&h);
}

__device__ __forceinline__ void gld_lds16(const void* g, void* l) {
  __builtin_amdgcn_global_load_lds(
      (const __attribute__((address_space(1))) void*)g,
      (__attribute__((address_space(3))) void*)l, 16, 0, 0);
}

// ---------------- fp32 -> bf16 convert ----------------
__global__ void k_cvt(const float* __restrict__ src, unsigned short* __restrict__ dst, int n4) {
  int i = blockIdx.x * blockDim.x + threadIdx.x;
  int stride = gridDim.x * blockDim.x;
  for (; i < n4; i += stride) {
    float4 v = reinterpret_cast<const float4*>(src)[i];
    ushort4 o;
    o.x = f2b(v.x); o.y = f2b(v.y); o.z = f2b(v.z); o.w = f2b(v.w);
    reinterpret_cast<ushort4*>(dst)[i] = o;
  }
}

// ---------------- QKV projection GEMM: Y = X(M,K) * W(N,K)^T ----------------
// m97 structure: 128x128 tile, BK=32, global_load_lds width 16, 4 waves 2x2,
// each wave 64x64 = 4x4 frags of mfma_f32_16x16x32_bf16.
// z=2 (V) stores transposed: Vt[b][d][t].
__launch_bounds__(256)
__global__ void k_qkv(const unsigned short* __restrict__ xb,
                      const unsigned short* __restrict__ wqb,
                      const unsigned short* __restrict__ wkb,
                      const unsigned short* __restrict__ wvb,
                      unsigned short* __restrict__ Qb,
                      unsigned short* __restrict__ Kb,
                      unsigned short* __restrict__ Vt) {
  __shared__ __align__(16) unsigned short As[128*32];
  __shared__ __align__(16) unsigned short Bs[128*32];
  const int tid = threadIdx.x;
  const int l = tid & 63, wid = tid >> 6;
  const int z = blockIdx.z;
  const unsigned short* W = (z == 0) ? wqb : (z == 1) ? wkb : wvb;
  unsigned short* out = (z == 0) ? Qb : (z == 1) ? Kb : Vt;
  const long m0 = (long)blockIdx.x * 128;
  const long n0 = (long)blockIdx.y * 128;
  const int l15 = l & 15, l4 = l >> 4;
  const int wr = (wid >> 1) * 64, wc = (wid & 1) * 64;

  // staging coords: thread t -> row t/4, col (t%4)*8 (8 bf16 = 16B)
  const int lrow = tid >> 2;
  const int lcol = (tid & 3) * 8;
  const unsigned short* Ap = xb + (m0 + lrow) * DD + lcol;
  const unsigned short* Wp = W  + (n0 + lrow) * DD + lcol;
  unsigned short* AsW = &As[wid * 512];   // wave-uniform LDS base, lane writes base + lane*16B
  unsigned short* BsW = &Bs[wid * 512];

  f32x4 acc[4][4] = {};

  for (int k0 = 0; k0 < DD; k0 += 32) {
    __syncthreads();                       // prev-iter frag reads done
    gld_lds16(Ap + k0,           AsW);
    gld_lds16(Ap + 64*DD + k0,   AsW + 2048);
    gld_lds16(Wp + k0,           BsW);
    gld_lds16(Wp + 64*DD + k0,   BsW + 2048);
    __syncthreads();                       // drains vmcnt -> LDS tiles ready
    bf16x8 af[4], bfr[4];
    #pragma unroll
    for (int mi = 0; mi < 4; ++mi)
      af[mi] = *reinterpret_cast<const bf16x8*>(&As[(wr + mi*16 + l15)*32 + l4*8]);
    #pragma unroll
    for (int ni = 0; ni < 4; ++ni)
      bfr[ni] = *reinterpret_cast<const bf16x8*>(&Bs[(wc + ni*16 + l15)*32 + l4*8]);
    #pragma unroll
    for (int mi = 0; mi < 4; ++mi)
      #pragma unroll
      for (int ni = 0; ni < 4; ++ni)
        acc[mi][ni] = __builtin_amdgcn_mfma_f32_16x16x32_bf16(af[mi], bfr[ni], acc[mi][ni], 0, 0, 0);
  }

  // C/D layout: row = (l>>4)*4 + r, col = l&15  (m89/m91 verified)
  if (z < 2) {
    #pragma unroll
    for (int mi = 0; mi < 4; ++mi)
      #pragma unroll
      for (int ni = 0; ni < 4; ++ni)
        #pragma unroll
        for (int r = 0; r < 4; ++r) {
          long row = m0 + wr + mi*16 + l4*4 + r;
          long col = n0 + wc + ni*16 + l15;
          out[row * DD + col] = f2b(acc[mi][ni][r]);
        }
  } else {
    #pragma unroll
    for (int mi = 0; mi < 4; ++mi)
      #pragma unroll
      for (int ni = 0; ni < 4; ++ni)
        #pragma unroll
        for (int r = 0; r < 4; ++r) {
          long row = m0 + wr + mi*16 + l4*4 + r;
          long col = n0 + wc + ni*16 + l15;
          long b = row >> 11, t = row & (TT - 1);
          out[(b * DD + col) * TT + t] = f2b(acc[mi][ni][r]);   // Vt[b][d][t]
        }
  }
}

// ---------------- fused causal flash attention ----------------
// Block: batch bb, q rows [q0, q0+32). 512 threads = 8 waves.
// QK^T: wave w owns kv cols [w*16, w*16+16) of the 128-wide KV tile, full d=1024
//       reduction via LDS K chunks of 128.
// PV:   wave w owns d cols [w*128, w*128+128); V read direct from Vt (k-contig).
__launch_bounds__(512)
__global__ void k_flash(const unsigned short* __restrict__ Qb,
                        const unsigned short* __restrict__ Kb,
                        const unsigned short* __restrict__ Vt,
                        float* __restrict__ O) {
  constexpr int KBL = 128, DC = 128;
  __shared__ __align__(16) unsigned short Kc[KBL][DC + 8];    // 34816 B, pad vs bank conflicts
  __shared__ float S_s[QBLK][KBL + 4];                        // 16896 B
  __shared__ __align__(16) unsigned short P_s[QBLK][KBL + 8]; // 8704 B
  __shared__ float m_s[QBLK], l_s[QBLK], al_s[QBLK];

  const int tid = threadIdx.x;
  const int l = tid & 63, wid = tid >> 6;
  const int l15 = l & 15, l4 = l >> 4;
  const int bb = blockIdx.y;
  const int q0 = blockIdx.x * QBLK;
  const float scale = 0.03125f;   // 1/sqrt(1024)

  if (tid < QBLK) { m_s[tid] = -1e30f; l_s[tid] = 0.f; al_s[tid] = 0.f; }
  __syncthreads();

  f32x4 acc[2][8] = {};

  const size_t qrow0 = (size_t)bb * TT + q0;
  const size_t kbase = (size_t)bb * TT * DD;
  const size_t vbase = (size_t)bb * DD * TT;

  const int sr = tid >> 4;          // staging: 32 rows/iter, 4 iters
  const int sc = (tid & 15) * 8;    // 8 bf16 = 16B

  const int nkv = (q0 + QBLK + KBL - 1) / KBL;

  for (int tk = 0; tk < nkv; ++tk) {
    const int kv0 = tk * KBL;
    f32x4 sa[2] = {};
    // ---- QK^T over d chunks ----
    for (int dc = 0; dc < DD; dc += DC) {
      uint4 kr[4];
      #pragma unroll
      for (int it = 0; it < 4; ++it)
        kr[it] = *reinterpret_cast<const uint4*>(
            &Kb[kbase + (size_t)(kv0 + sr + it*32)*DD + dc + sc]);
      bf16x8 aq[2][4];
      #pragma unroll
      for (int mi = 0; mi < 2; ++mi)
        #pragma unroll
        for (int kk = 0; kk < 4; ++kk)
          aq[mi][kk] = *reinterpret_cast<const bf16x8*>(
              &Qb[(qrow0 + mi*16 + l15)*DD + dc + kk*32 + l4*8]);
      __syncthreads();                 // prev-chunk reads done before overwrite
      #pragma unroll
      for (int it = 0; it < 4; ++it)
        *reinterpret_cast<uint4*>(&Kc[sr + it*32][sc]) = kr[it];
      __syncthreads();
      #pragma unroll
      for (int kk = 0; kk < 4; ++kk) {
        bf16x8 bk = *reinterpret_cast<const bf16x8*>(&Kc[wid*16 + l15][kk*32 + l4*8]);
        #pragma unroll
        for (int mi = 0; mi < 2; ++mi)
          sa[mi] = __builtin_amdgcn_mfma_f32_16x16x32_bf16(aq[mi][kk], bk, sa[mi], 0, 0, 0);
      }
    }
    // ---- write S (scale + causal mask) ----
    #pragma unroll
    for (int mi = 0; mi < 2; ++mi)
      #pragma unroll
      for (int r = 0; r < 4; ++r) {
        int qr = mi*16 + l4*4 + r;
        int kc = wid*16 + l15;
        float v = sa[mi][r] * scale;
        if (kv0 + kc > q0 + qr) v = -1e30f;
        S_s[qr][kc] = v;
      }
    __syncthreads();
    // ---- online softmax: 32 rows x 16 lanes ----
    {
      const int row = tid >> 4, lr = tid & 15;
      float pv[8]; float vmax = -1e30f;
      #pragma unroll
      for (int j = 0; j < 8; ++j) { pv[j] = S_s[row][lr + j*16]; vmax = fmaxf(vmax, pv[j]); }
      #pragma unroll
      for (int mm = 1; mm < 16; mm <<= 1) vmax = fmaxf(vmax, __shfl_xor(vmax, mm));
      const float mo = m_s[row];
      const float mn = fmaxf(mo, vmax);
      const float al = __expf(mo - mn);
      float s = 0.f;
      #pragma unroll
      for (int j = 0; j < 8; ++j) {
        float p = __expf(pv[j] - mn);
        s += p;
        P_s[row][lr + j*16] = f2b(p);
      }
      #pragma unroll
      for (int mm = 1; mm < 16; mm <<= 1) s += __shfl_xor(s, mm);
      if (lr == 0) { m_s[row] = mn; l_s[row] = l_s[row] * al + s; al_s[row] = al; }
    }
    __syncthreads();
    // ---- rescale O, then PV ----
    #pragma unroll
    for (int mi = 0; mi < 2; ++mi)
      #pragma unroll
      for (int r = 0; r < 4; ++r) {
        const float al = al_s[mi*16 + l4*4 + r];
        #pragma unroll
        for (int ni = 0; ni < 8; ++ni) acc[mi][ni][r] *= al;
      }
    #pragma unroll
    for (int kk = 0; kk < 4; ++kk) {
      bf16x8 ap[2];
      #pragma unroll
      for (int mi = 0; mi < 2; ++mi)
        ap[mi] = *reinterpret_cast<const bf16x8*>(&P_s[mi*16 + l15][kk*32 + l4*8]);
      #pragma unroll
      for (int ni = 0; ni < 8; ++ni) {
        bf16x8 bv = *reinterpret_cast<const bf16x8*>(
            &Vt[vbase + (size_t)(wid*128 + ni*16 + l15)*TT + kv0 + kk*32 + l4*8]);
        #pragma unroll
        for (int mi = 0; mi < 2; ++mi)
          acc[mi][ni] = __builtin_amdgcn_mfma_f32_16x16x32_bf16(ap[mi], bv, acc[mi][ni], 0, 0, 0);
      }
    }
  }
  // ---- epilogue: O = acc / l ----
  #pragma unroll
  for (int mi = 0; mi < 2; ++mi)
    #pragma unroll
    for (int r = 0; r < 4; ++r) {
      const int qr = mi*16 + l4*4 + r;
      const float rl = 1.0f / l_s[qr];
      #pragma unroll
      for (int ni = 0; ni < 8; ++ni)
        O[(qrow0 + qr) * DD + wid*128 + ni*16 + l15] = acc[mi][ni][r] * rl;
    }
}

extern "C" void kernel_launch(void* const* d_in, const int* in_sizes, int n_in,
                              void* d_out, int out_size, void* d_ws, size_t ws_size,
                              hipStream_t stream) {
  const float* x  = (const float*)d_in[0];
  const float* wq = (const float*)d_in[1];
  const float* wk = (const float*)d_in[2];
  const float* wv = (const float*)d_in[3];
  unsigned short* ws  = (unsigned short*)d_ws;
  unsigned short* xb  = ws;                          // MM*DD bf16
  unsigned short* wqb = xb  + (size_t)MM * DD;       // DD*DD
  unsigned short* wkb = wqb + (size_t)DD * DD;
  unsigned short* wvb = wkb + (size_t)DD * DD;
  unsigned short* Qb  = wvb + (size_t)DD * DD;       // MM*DD
  unsigned short* Kb  = Qb  + (size_t)MM * DD;       // MM*DD
  unsigned short* Vt  = Kb  + (size_t)MM * DD;       // MM*DD, [B][D][T]
  float* out = (float*)d_out;

  k_cvt<<<1024, 256, 0, stream>>>(x,  xb,  MM*DD/4);
  k_cvt<<<256,  256, 0, stream>>>(wq, wqb, DD*DD/4);
  k_cvt<<<256,  256, 0, stream>>>(wk, wkb, DD*DD/4);
  k_cvt<<<256,  256, 0, stream>>>(wv, wvb, DD*DD/4);
  k_qkv<<<dim3(MM/128, DD/128, 3), 256, 0, stream>>>(xb, wqb, wkb, wvb, Qb, Kb, Vt);
  k_flash<<<dim3(TT/QBLK, NB), 512, 0, stream>>>(Qb, Kb, Vt, out);
}

// Round 3
// 187.369 us; speedup vs baseline: 4.3838x; 4.3838x over previous
//
#include <hip/hip_runtime.h>
#include <hip/hip_bf16.h>

#define NB 4
#define TT 2048
#define DD 1024
#define MM (NB*TT)

using f32x4  = __attribute__((ext_vector_type(4))) float;
using bf16x8 = __attribute__((ext_vector_type(8))) __bf16;
using u16x8  = __attribute__((ext_vector_type(8))) unsigned short;

__device__ __forceinline__ unsigned short f2b(float f) {
  __hip_bfloat16 h = __float2bfloat16(f);
  return *reinterpret_cast<unsigned short*>(&h);
}

__device__ __forceinline__ float b2f(unsigned short u) {
  __hip_bfloat16 h = *reinterpret_cast<__hip_bfloat16*>(&u);
  return __bfloat162float(h);
}

__device__ __forceinline__ void gld_lds16(const void* g, void* l) {
  __builtin_amdgcn_global_load_lds(
      (const __attribute__((address_space(1))) void*)g,
      (__attribute__((address_space(3))) void*)l, 16, 0, 0);
}

// ---------------- fp32 -> bf16 convert ----------------
__global__ void k_cvt(const float* __restrict__ src, unsigned short* __restrict__ dst, int n4) {
  int i = blockIdx.x * blockDim.x + threadIdx.x;
  int stride = gridDim.x * blockDim.x;
  for (; i < n4; i += stride) {
    float4 v = reinterpret_cast<const float4*>(src)[i];
    ushort4 o;   // 4 elements, matches float4's 4 lanes
    o.x = f2b(v.x); o.y = f2b(v.y); o.z = f2b(v.z); o.w = f2b(v.w);
    reinterpret_cast<ushort4*>(dst)[i] = o;
  }
}

// ---------------- QKV projection GEMM: Y = X(M,K) * W(N,K)^T ----------------
// m97 structure: 128x128 tile, BK=32, global_load_lds width 16, 4 waves 2x2.
// z=2 (V) stores transposed: Vt[b][d][t].
__launch_bounds__(256)
__global__ void k_qkv(const unsigned short* __restrict__ xb,
                      const unsigned short* __restrict__ wqb,
                      const unsigned short* __restrict__ wkb,
                      const unsigned short* __restrict__ wvb,
                      unsigned short* __restrict__ Qb,
                      unsigned short* __restrict__ Kb,
                      unsigned short* __restrict__ Vt) {
  __shared__ __align__(16) unsigned short As[128*32];
  __shared__ __align__(16) unsigned short Bs[128*32];
  const int tid = threadIdx.x;
  const int l = tid & 63, wid = tid >> 6;
  const int z = blockIdx.z;
  const unsigned short* W = (z == 0) ? wqb : (z == 1) ? wkb : wvb;
  unsigned short* out = (z == 0) ? Qb : (z == 1) ? Kb : Vt;
  const long m0 = (long)blockIdx.x * 128;
  const long n0 = (long)blockIdx.y * 128;
  const int l15 = l & 15, l4 = l >> 4;
  const int wr = (wid >> 1) * 64, wc = (wid & 1) * 64;

  const int lrow = tid >> 2;
  const int lcol = (tid & 3) * 8;
  const unsigned short* Ap = xb + (m0 + lrow) * DD + lcol;
  const unsigned short* Wp = W  + (n0 + lrow) * DD + lcol;
  unsigned short* AsW = &As[wid * 512];
  unsigned short* BsW = &Bs[wid * 512];

  f32x4 acc[4][4] = {};

  for (int k0 = 0; k0 < DD; k0 += 32) {
    __syncthreads();
    gld_lds16(Ap + k0,           AsW);
    gld_lds16(Ap + 64*DD + k0,   AsW + 2048);
    gld_lds16(Wp + k0,           BsW);
    gld_lds16(Wp + 64*DD + k0,   BsW + 2048);
    __syncthreads();
    bf16x8 af[4], bfr[4];
    #pragma unroll
    for (int mi = 0; mi < 4; ++mi)
      af[mi] = *reinterpret_cast<const bf16x8*>(&As[(wr + mi*16 + l15)*32 + l4*8]);
    #pragma unroll
    for (int ni = 0; ni < 4; ++ni)
      bfr[ni] = *reinterpret_cast<const bf16x8*>(&Bs[(wc + ni*16 + l15)*32 + l4*8]);
    #pragma unroll
    for (int mi = 0; mi < 4; ++mi)
      #pragma unroll
      for (int ni = 0; ni < 4; ++ni)
        acc[mi][ni] = __builtin_amdgcn_mfma_f32_16x16x32_bf16(af[mi], bfr[ni], acc[mi][ni], 0, 0, 0);
  }

  if (z < 2) {
    #pragma unroll
    for (int mi = 0; mi < 4; ++mi)
      #pragma unroll
      for (int ni = 0; ni < 4; ++ni)
        #pragma unroll
        for (int r = 0; r < 4; ++r) {
          long row = m0 + wr + mi*16 + l4*4 + r;
          long col = n0 + wc + ni*16 + l15;
          out[row * DD + col] = f2b(acc[mi][ni][r]);
        }
  } else {
    #pragma unroll
    for (int mi = 0; mi < 4; ++mi)
      #pragma unroll
      for (int ni = 0; ni < 4; ++ni)
        #pragma unroll
        for (int r = 0; r < 4; ++r) {
          long row = m0 + wr + mi*16 + l4*4 + r;
          long col = n0 + wc + ni*16 + l15;
          long b = row >> 11, t = row & (TT - 1);
          out[(b * DD + col) * TT + t] = f2b(acc[mi][ni][r]);   // Vt[b][d][t]
        }
  }
}

// ---------------- S = scale * Q K^T (causal tiles only), bf16 out ----------------
// One block per causal 128x128 tile: 544 blocks (4 batches x 136 tiles).
__launch_bounds__(256)
__global__ void k_scores(const unsigned short* __restrict__ Qb,
                         const unsigned short* __restrict__ Kb,
                         unsigned short* __restrict__ S) {
  __shared__ __align__(16) unsigned short As[128*32];
  __shared__ __align__(16) unsigned short Bs[128*32];
  const int tid = threadIdx.x;
  const int l = tid & 63, wid = tid >> 6;
  const int l15 = l & 15, l4 = l >> 4;
  const int wr = (wid >> 1) * 64, wc = (wid & 1) * 64;

  const int b = blockIdx.x / 136;
  int t = blockIdx.x % 136;
  int qi = 0;
  while ((qi + 1) * (qi + 2) / 2 <= t) qi++;   // triangular decode, qi in [0,15]
  const int ki = t - qi * (qi + 1) / 2;

  const size_t arow0 = (size_t)b * TT + qi * 128;
  const size_t brow0 = (size_t)b * TT + ki * 128;

  const int lrow = tid >> 2;
  const int lcol = (tid & 3) * 8;
  const unsigned short* Ap = Qb + (arow0 + lrow) * DD + lcol;
  const unsigned short* Bp = Kb + (brow0 + lrow) * DD + lcol;
  unsigned short* AsW = &As[wid * 512];
  unsigned short* BsW = &Bs[wid * 512];

  f32x4 acc[4][4] = {};

  for (int k0 = 0; k0 < DD; k0 += 32) {
    __syncthreads();
    gld_lds16(Ap + k0,           AsW);
    gld_lds16(Ap + 64*DD + k0,   AsW + 2048);
    gld_lds16(Bp + k0,           BsW);
    gld_lds16(Bp + 64*DD + k0,   BsW + 2048);
    __syncthreads();
    bf16x8 af[4], bfr[4];
    #pragma unroll
    for (int mi = 0; mi < 4; ++mi)
      af[mi] = *reinterpret_cast<const bf16x8*>(&As[(wr + mi*16 + l15)*32 + l4*8]);
    #pragma unroll
    for (int ni = 0; ni < 4; ++ni)
      bfr[ni] = *reinterpret_cast<const bf16x8*>(&Bs[(wc + ni*16 + l15)*32 + l4*8]);
    #pragma unroll
    for (int mi = 0; mi < 4; ++mi)
      #pragma unroll
      for (int ni = 0; ni < 4; ++ni)
        acc[mi][ni] = __builtin_amdgcn_mfma_f32_16x16x32_bf16(af[mi], bfr[ni], acc[mi][ni], 0, 0, 0);
  }

  const float scale = 0.03125f;   // 1/sqrt(1024)
  #pragma unroll
  for (int mi = 0; mi < 4; ++mi)
    #pragma unroll
    for (int ni = 0; ni < 4; ++ni)
      #pragma unroll
      for (int r = 0; r < 4; ++r) {
        int row = wr + mi*16 + l4*4 + r;
        int col = wc + ni*16 + l15;
        int gq = qi*128 + row, gk = ki*128 + col;
        float v = (gk > gq) ? -1e30f : acc[mi][ni][r] * scale;
        S[((size_t)b * TT + gq) * TT + gk] = f2b(v);
      }
}

// ---------------- rowwise softmax in place: P = exp(S - m), rl = 1/sum ----------------
// One wave per row; row (<=2048 bf16) held in registers as 4 x u16x8 (16B) per lane.
__launch_bounds__(256)
__global__ void k_softmax(unsigned short* __restrict__ S, float* __restrict__ rl) {
  const int tid = threadIdx.x;
  const int w = tid >> 6, l = tid & 63;
  const int row = blockIdx.x * 4 + w;          // 0..MM-1
  const int b = row >> 11, q = row & (TT - 1);
  unsigned short* Srow = S + ((size_t)b * TT + q) * TT;
  const int width = ((q >> 7) + 1) << 7;       // padded causal extent (mult of 128)

  float v[4][8];
  bool has[4];
  float mx = -1e30f;
  #pragma unroll
  for (int c = 0; c < 4; ++c) {
    const int off = c * 512 + l * 8;
    has[c] = off < width;
    if (has[c]) {
      u16x8 u = *reinterpret_cast<const u16x8*>(&Srow[off]);   // 8 bf16 = 16B
      #pragma unroll
      for (int j = 0; j < 8; ++j) { v[c][j] = b2f(u[j]); mx = fmaxf(mx, v[c][j]); }
    }
  }
  #pragma unroll
  for (int mm = 1; mm < 64; mm <<= 1) mx = fmaxf(mx, __shfl_xor(mx, mm));

  float s = 0.f;
  #pragma unroll
  for (int c = 0; c < 4; ++c) {
    if (has[c]) {
      u16x8 u;
      #pragma unroll
      for (int j = 0; j < 8; ++j) {
        float p = __expf(v[c][j] - mx);
        s += p;
        u[j] = f2b(p);
      }
      *reinterpret_cast<u16x8*>(&Srow[c * 512 + l * 8]) = u;
    }
  }
  #pragma unroll
  for (int mm = 1; mm < 64; mm <<= 1) s += __shfl_xor(s, mm);
  if (l == 0) rl[row] = 1.0f / s;
}

// ---------------- O = (P Vt^T) * rl : per-batch GEMM over causal extent ----------------
// Block = (b, q-tile qi, d-tile di); longest qi dispatched first.
__launch_bounds__(256)
__global__ void k_pv(const unsigned short* __restrict__ P,
                     const unsigned short* __restrict__ Vt,
                     const float* __restrict__ rl,
                     float* __restrict__ O) {
  __shared__ __align__(16) unsigned short As[128*32];
  __shared__ __align__(16) unsigned short Bs[128*32];
  const int tid = threadIdx.x;
  const int l = tid & 63, wid = tid >> 6;
  const int l15 = l & 15, l4 = l >> 4;
  const int wr = (wid >> 1) * 64, wc = (wid & 1) * 64;

  const int qi = 15 - (blockIdx.x >> 5);       // heaviest first
  const int di = (blockIdx.x >> 2) & 7;
  const int b  = blockIdx.x & 3;
  const int KEXT = (qi + 1) * 128;

  const int lrow = tid >> 2;
  const int lcol = (tid & 3) * 8;
  const unsigned short* Ap = P  + ((size_t)b * TT + qi * 128 + lrow) * TT + lcol;
  const unsigned short* Bp = Vt + ((size_t)b * DD + di * 128 + lrow) * TT + lcol;
  unsigned short* AsW = &As[wid * 512];
  unsigned short* BsW = &Bs[wid * 512];

  f32x4 acc[4][4] = {};

  for (int k0 = 0; k0 < KEXT; k0 += 32) {
    __syncthreads();
    gld_lds16(Ap + k0,           AsW);
    gld_lds16(Ap + 64*TT + k0,   AsW + 2048);
    gld_lds16(Bp + k0,           BsW);
    gld_lds16(Bp + 64*TT + k0,   BsW + 2048);
    __syncthreads();
    bf16x8 af[4], bfr[4];
    #pragma unroll
    for (int mi = 0; mi < 4; ++mi)
      af[mi] = *reinterpret_cast<const bf16x8*>(&As[(wr + mi*16 + l15)*32 + l4*8]);
    #pragma unroll
    for (int ni = 0; ni < 4; ++ni)
      bfr[ni] = *reinterpret_cast<const bf16x8*>(&Bs[(wc + ni*16 + l15)*32 + l4*8]);
    #pragma unroll
    for (int mi = 0; mi < 4; ++mi)
      #pragma unroll
      for (int ni = 0; ni < 4; ++ni)
        acc[mi][ni] = __builtin_amdgcn_mfma_f32_16x16x32_bf16(af[mi], bfr[ni], acc[mi][ni], 0, 0, 0);
  }

  #pragma unroll
  for (int mi = 0; mi < 4; ++mi)
    #pragma unroll
    for (int ni = 0; ni < 4; ++ni)
      #pragma unroll
      for (int r = 0; r < 4; ++r) {
        int row = wr + mi*16 + l4*4 + r;
        int col = wc + ni*16 + l15;
        size_t q = (size_t)qi * 128 + row;
        O[((size_t)b * TT + q) * DD + di * 128 + col] =
            acc[mi][ni][r] * rl[(size_t)b * TT + q];
      }
}

extern "C" void kernel_launch(void* const* d_in, const int* in_sizes, int n_in,
                              void* d_out, int out_size, void* d_ws, size_t ws_size,
                              hipStream_t stream) {
  const float* x  = (const float*)d_in[0];
  const float* wq = (const float*)d_in[1];
  const float* wk = (const float*)d_in[2];
  const float* wv = (const float*)d_in[3];
  unsigned short* ws  = (unsigned short*)d_ws;
  // Layout (bf16 elements):
  //   [Qb: MM*DD][Kb: MM*DD][Vt: MM*DD][S: NB*TT*TT][rl: MM floats]
  // xb/wqb/wkb/wvb alias the S region (dead once k_qkv completes).
  unsigned short* Qb  = ws;
  unsigned short* Kb  = Qb + (size_t)MM * DD;
  unsigned short* Vt  = Kb + (size_t)MM * DD;
  unsigned short* Sb  = Vt + (size_t)MM * DD;        // NB*TT*TT elems
  unsigned short* xb  = Sb;                          // alias
  unsigned short* wqb = xb + (size_t)MM * DD;
  unsigned short* wkb = wqb + (size_t)DD * DD;
  unsigned short* wvb = wkb + (size_t)DD * DD;
  float* rl = (float*)(Sb + (size_t)NB * TT * TT);
  float* out = (float*)d_out;

  k_cvt<<<1024, 256, 0, stream>>>(x,  xb,  MM*DD/4);
  k_cvt<<<256,  256, 0, stream>>>(wq, wqb, DD*DD/4);
  k_cvt<<<256,  256, 0, stream>>>(wk, wkb, DD*DD/4);
  k_cvt<<<256,  256, 0, stream>>>(wv, wvb, DD*DD/4);
  k_qkv<<<dim3(MM/128, DD/128, 3), 256, 0, stream>>>(xb, wqb, wkb, wvb, Qb, Kb, Vt);
  k_scores<<<544, 256, 0, stream>>>(Qb, Kb, Sb);
  k_softmax<<<MM/4, 256, 0, stream>>>(Sb, rl);
  k_pv<<<512, 256, 0, stream>>>(Sb, Vt, rl, out);
}